// Round 21
// baseline (132.197 us; speedup 1.0000x reference)
//
#include <hip/hip_runtime.h>

#define BATCH 4
#define NN 512
#define HID 256
#define EDIM 16
#define HEADS 8
#define HDIM 32

typedef __attribute__((ext_vector_type(8))) short bf16x8;
typedef __attribute__((ext_vector_type(4))) float f32x4;

__device__ inline unsigned short bf16_hi(float x){ return (unsigned short)(__float_as_uint(x)>>16); }
__device__ inline float bf16_f(unsigned short s){ return __uint_as_float(((unsigned)s)<<16); }
__device__ inline unsigned short bf16_rn(float x){
    unsigned u = __float_as_uint(x);
    unsigned r = u + 0x7FFFu + ((u>>16)&1u);
    return (unsigned short)(r>>16);
}
__device__ inline unsigned cvt_pk_bf16(float a, float b){
    unsigned d;
    asm("v_cvt_pk_bf16_f32 %0, %1, %2" : "=v"(d) : "v"(a), "v"(b));
    return d;
}
// split 8 floats into hi (trunc) and lo (RNE of remainder) bf16x8 fragments
__device__ inline void hilo8(float4 A, float4 B, bf16x8& hi, bf16x8& lo){
    float xs[8] = {A.x,A.y,A.z,A.w,B.x,B.y,B.z,B.w};
    unsigned hu[4], lu[4];
#pragma unroll
    for (int p = 0; p < 4; ++p){
        unsigned u0 = __float_as_uint(xs[2*p]), u1 = __float_as_uint(xs[2*p+1]);
        float h0 = __uint_as_float(u0 & 0xFFFF0000u);
        float h1 = __uint_as_float(u1 & 0xFFFF0000u);
        hu[p] = (u0 >> 16) | (u1 & 0xFFFF0000u);
        lu[p] = cvt_pk_bf16(xs[2*p] - h0, xs[2*p+1] - h1);
    }
    int4 hv; hv.x = hu[0]; hv.y = hu[1]; hv.z = hu[2]; hv.w = hu[3];
    int4 lv; lv.x = lu[0]; lv.y = lu[1]; lv.z = lu[2]; lv.w = lu[3];
    hi = *(bf16x8*)&hv; lo = *(bf16x8*)&lv;
}

// ---------- kernel 0: pack W1 (K=32: [W1hi(16); W1lo(15); be1]) + W2 bf16 B-frags ----------
__global__ void k_pack(const float* __restrict__ We1, const float* __restrict__ be1,
                       const float* __restrict__ We2,
                       unsigned short* __restrict__ W1P, unsigned short* __restrict__ W2P) {
    int t = threadIdx.x;  // 256
#pragma unroll
    for (int rep = 0; rep < 4; ++rep) {
        int p = rep * 256 + t;          // (ut, lane)
        int ut = p >> 6, lane = p & 63;
        int q = lane >> 4, r = lane & 15;
        int unit = ut * 16 + r;
#pragma unroll
        for (int j = 0; j < 8; ++j) {
            int k = q * 8 + j;
            unsigned short ov;
            if (k < 16) ov = bf16_hi(We1[k * HID + unit]);
            else if (k < 31) {
                float v = We1[(k - 16) * HID + unit];
                ov = bf16_rn(v - bf16_f(bf16_hi(v)));
            } else ov = bf16_rn(be1[unit]);
            W1P[p * 8 + j] = ov;
        }
    }
#pragma unroll
    for (int rep = 0; rep < 2; ++rep) {
        int p = rep * 256 + t;          // (kt, lane)
        int kt = p >> 6, lane = p & 63;
        int q = lane >> 4, r = lane & 15;
#pragma unroll
        for (int jj = 0; jj < 8; ++jj) {
            int unit = kt * 32 + q * 8 + jj;
            W2P[p * 8 + jj] = (r < 8) ? bf16_rn(We2[unit * HEADS + r]) : (unsigned short)0;
        }
    }
}

// ---------- kernel 1: FUSED eb + qkv (independent work, co-scheduled; R20 win) ----------
__global__ __launch_bounds__(256, 3) void k_ebqkv(
    const float* __restrict__ edge_x,
    const unsigned short* __restrict__ W1P, const unsigned short* __restrict__ W2P,
    const float* __restrict__ be2, float* __restrict__ eb,
    const float* __restrict__ node_h,
    const float* __restrict__ Wq, const float* __restrict__ bq,
    const float* __restrict__ Wk, const float* __restrict__ bk,
    const float* __restrict__ Wv, const float* __restrict__ bv,
    float* __restrict__ q,
    unsigned short* __restrict__ khi, unsigned short* __restrict__ klo,
    unsigned short* __restrict__ vhi, unsigned short* __restrict__ vlo) {
    __shared__ __align__(16) char smem[24576];   // overlay: eb 24 KB | qkv 4 KB
    int bid0 = blockIdx.x;
    int g5 = bid0 / 5, m5 = bid0 % 5;
    int t = threadIdx.x;

    if (m5 == 4) {
        // ================= qkv body (verbatim R13), blk = g5 in [0,512) =================
        float (*s_h)[HID] = (float(*)[HID])smem;
        int blk = g5;
        int b = blk >> 7, i0 = (blk & 127) << 2;
#pragma unroll
        for (int u = 0; u < 4; ++u)
            s_h[u][t] = node_h[((size_t)b * NN + i0 + u) * HID + t];
        __syncthreads();
        float aq[4], ak[4], av[4];
        float bqv = bq[t], bkv = bk[t], bvv = bv[t];
#pragma unroll
        for (int u = 0; u < 4; ++u) { aq[u] = bqv; ak[u] = bkv; av[u] = bvv; }
#pragma unroll 4
        for (int rr = 0; rr < HID; ++rr) {
            float wq = Wq[rr * HID + t], wk = Wk[rr * HID + t], wv = Wv[rr * HID + t];
#pragma unroll
            for (int u = 0; u < 4; ++u) {
                float x = s_h[u][rr];
                aq[u] = fmaf(x, wq, aq[u]);
                ak[u] = fmaf(x, wk, ak[u]);
                av[u] = fmaf(x, wv, av[u]);
            }
        }
        int h = t >> 5, d = t & 31;
#pragma unroll
        for (int u = 0; u < 4; ++u) {
            size_t idx = ((size_t)(b * HEADS + h) * NN + i0 + u) * HDIM + d;
            q[idx] = aq[u];
            unsigned short kh = bf16_hi(ak[u]);
            khi[idx] = kh;
            klo[idx] = bf16_rn(ak[u] - bf16_f(kh));
            size_t vidx = ((size_t)(b * HEADS + h) * HDIM + d) * NN + i0 + u;
            unsigned short vh = bf16_hi(av[u]);
            vhi[vidx] = vh;
            vlo[vidx] = bf16_rn(av[u] - bf16_f(vh));
        }
        return;
    }

    // ================= eb body (verbatim R13/R15), eid = g5*4 + m5 in [0,2048) =================
    unsigned short* sW1 = (unsigned short*)smem;            // 16 KB
    unsigned short* sW2 = (unsigned short*)(smem + 16384);  // 8 KB
    int eid = g5 * 4 + m5;
    int b = eid >> 9, i0 = ((eid >> 2) & 127) << 2, jq = eid & 3;
    int w = t >> 6, lane = t & 63;
    int q2 = lane >> 4, r = lane & 15;

    {
        const float4* s1 = (const float4*)W1P;
        float4* d1 = (float4*)sW1;
#pragma unroll
        for (int rep = 0; rep < 4; ++rep) d1[rep * 256 + t] = s1[rep * 256 + t];
        const float4* s2 = (const float4*)W2P;
        float4* d2 = (float4*)sW2;
#pragma unroll
        for (int rep = 0; rep < 2; ++rep) d2[rep * 256 + t] = s2[rep * 256 + t];
    }
    __syncthreads();

    float be2r = (r < 8) ? be2[r] : 0.f;
    const char* wb1 = (const char*)sW1 + lane * 16;
    const char* wb2 = (const char*)sW2 + lane * 16;

    size_t xbase = (((size_t)b * NN + i0 + w) * NN) * EDIM + (size_t)((q2 & 1) * 8);
    const f32x4 zero4 = {0.f, 0.f, 0.f, 0.f};

    for (int sc = 0; sc < 2; ++sc) {
        int cc0 = jq * 8 + sc * 4;
        float4 xv[8];
#pragma unroll
        for (int x = 0; x < 4; ++x) {
            const float4* px = (const float4*)(edge_x + xbase + (size_t)((cc0 + x) * 16 + r) * EDIM);
            xv[2 * x]     = px[0];
            xv[2 * x + 1] = px[1];
        }
        bf16x8 bx[4];
#pragma unroll
        for (int x = 0; x < 4; ++x) {
            unsigned u0 = cvt_pk_bf16(xv[2*x].x, xv[2*x].y);
            unsigned u1 = cvt_pk_bf16(xv[2*x].z, xv[2*x].w);
            unsigned u2 = cvt_pk_bf16(xv[2*x+1].x, xv[2*x+1].y);
            unsigned u3 = cvt_pk_bf16(xv[2*x+1].z, xv[2*x+1].w);
            if (q2 == 3) u3 = (u3 & 0xFFFFu) | 0x3F800000u;   // slot31 = 1.0 (be1)
            int4 bxi; bxi.x = u0; bxi.y = u1; bxi.z = u2; bxi.w = u3;
            bx[x] = *(bf16x8*)&bxi;
        }
        f32x4 acc0[4], acc1[4];
#pragma unroll
        for (int x = 0; x < 4; ++x) {
            acc0[x] = (f32x4){be2r, be2r, be2r, be2r};
            acc1[x] = zero4;
        }
#pragma unroll
        for (int ktp = 0; ktp < 8; ++ktp) {
            bf16x8 wa = *(const bf16x8*)(wb1 + (2 * ktp) * 1024);
            bf16x8 wb = *(const bf16x8*)(wb1 + (2 * ktp + 1) * 1024);
            bf16x8 w2 = *(const bf16x8*)(wb2 + ktp * 1024);
#pragma unroll
            for (int x = 0; x < 4; ++x) {
                f32x4 c0 = __builtin_amdgcn_mfma_f32_16x16x32_bf16(wa, bx[x], zero4, 0, 0, 0);
                f32x4 c1 = __builtin_amdgcn_mfma_f32_16x16x32_bf16(wb, bx[x], zero4, 0, 0, 0);
                unsigned P0 = cvt_pk_bf16(fmaxf(c0[0], 0.f), fmaxf(c0[1], 0.f));
                unsigned P1 = cvt_pk_bf16(fmaxf(c0[2], 0.f), fmaxf(c0[3], 0.f));
                unsigned Q0 = cvt_pk_bf16(fmaxf(c1[0], 0.f), fmaxf(c1[1], 0.f));
                unsigned Q1 = cvt_pk_bf16(fmaxf(c1[2], 0.f), fmaxf(c1[3], 0.f));
                // 16x16 transpose across the four 16-lane rows (zero LDS):
                asm("v_permlane32_swap_b32 %0, %1" : "+v"(P0), "+v"(Q0));
                asm("v_permlane16_swap_b32 %0, %1" : "+v"(P0), "+v"(Q0));
                asm("v_permlane32_swap_b32 %0, %1" : "+v"(P1), "+v"(Q1));
                asm("v_permlane16_swap_b32 %0, %1" : "+v"(P1), "+v"(Q1));
                int4 ai; ai.x = (int)P0; ai.y = (int)P1; ai.z = (int)Q0; ai.w = (int)Q1;
                if (ktp & 1)
                    acc1[x] = __builtin_amdgcn_mfma_f32_16x16x32_bf16(*(bf16x8*)&ai, w2, acc1[x], 0, 0, 0);
                else
                    acc0[x] = __builtin_amdgcn_mfma_f32_16x16x32_bf16(*(bf16x8*)&ai, w2, acc0[x], 0, 0, 0);
            }
        }
        if (r < 8) {
#pragma unroll
            for (int x = 0; x < 4; ++x) {
                f32x4 a = acc0[x] + acc1[x];
                *(f32x4*)(eb + (((size_t)(b * HEADS + r) * NN) + (i0 + w)) * NN + (cc0 + x) * 16 + q2 * 4) = a;
            }
        }
    }
}

// ---------- kernel 3: scores(MFMA) + softmax + attn@V(MFMA); fully-unrolled load loops ----------
__global__ __launch_bounds__(256, 4) void k_attn2(
    const int* __restrict__ emask, const float* __restrict__ q,
    const unsigned short* __restrict__ khi, const unsigned short* __restrict__ klo,
    const unsigned short* __restrict__ vhi, const unsigned short* __restrict__ vlo,
    float* attn, float* __restrict__ ao) {
    int orig = blockIdx.x;                      // 1024 blocks (1024 % 8 == 0: bijective)
    int bid = ((orig & 7) << 7) | (orig >> 3);  // xcd * 128 + orig/8
    int b = bid >> 8, h = (bid >> 5) & 7, ic = bid & 31;
    int i0 = ic << 4;
    int t = threadIdx.x, w = t >> 6, lane = t & 63;
    int q2 = lane >> 4, r = lane & 15;
    size_t bh = (size_t)b * HEADS + h;

    __shared__ __align__(16) float s_sc[16][516];   // 33024 B
    __shared__ float s_out[2][16][33];              // 4224 B
    char* sab = (char*)&s_sc[0][0];                 // row stride 2064 B

    // Q A-frag (hi/lo): lane 16*q2+r holds Q[row=r][d=q2*8..+7]
    bf16x8 qhi, qlo;
    {
        const float4* qp = (const float4*)(q + ((bh * NN) + i0 + r) * HDIM + q2 * 8);
        hilo8(qp[0], qp[1], qhi, qlo);
    }

    const float scale = 0.17677669529663687f;  // 1/sqrt(32)
    const int* mbase = emask + ((size_t)b * NN + i0) * NN;          // row i0, + (row)*NN + j
    const float* ebase = attn + (bh * NN + i0) * NN;                // eb rows
    // ---- QK^T + leaky + eb + mask; wave w: j-tiles w*8..w*8+7 (fully unrolled:
    //      all 16 K-loads + eb/mask loads become independent, issued in batches) ----
#pragma unroll
    for (int c = 0; c < 8; ++c) {
        int jt = w * 8 + c;
        size_t kidx = (bh * NN + jt * 16 + r) * HDIM + q2 * 8;
        bf16x8 kh8 = *(const bf16x8*)(khi + kidx);
        bf16x8 kl8 = *(const bf16x8*)(klo + kidx);
        f32x4 cc = {0.f, 0.f, 0.f, 0.f};
        cc = __builtin_amdgcn_mfma_f32_16x16x32_bf16(qhi, kh8, cc, 0, 0, 0);
        cc = __builtin_amdgcn_mfma_f32_16x16x32_bf16(qhi, kl8, cc, 0, 0, 0);
        cc = __builtin_amdgcn_mfma_f32_16x16x32_bf16(qlo, kh8, cc, 0, 0, 0);
        int j = jt * 16 + r;
#pragma unroll
        for (int reg = 0; reg < 4; ++reg) {
            int row = q2 * 4 + reg;
            float s = cc[reg] * scale;
            s = s > 0.f ? s : 0.2f * s;
            s += ebase[row * NN + j];
            bool valid = (mbase[row * NN + j] != 0) || (j == i0 + row);
            s_sc[row][j] = valid ? s : -1e9f;
        }
    }
    __syncthreads();

    // ---- softmax: wave w rows w*4..w*4+3; lane owns j = lane*8..lane*8+7 ----
#pragma unroll
    for (int rr = 0; rr < 4; ++rr) {
        int row = w * 4 + rr;
        f32x4 v0 = *(f32x4*)&s_sc[row][lane * 8];
        f32x4 v1 = *(f32x4*)&s_sc[row][lane * 8 + 4];
        float mx = fmaxf(fmaxf(fmaxf(v0[0], v0[1]), fmaxf(v0[2], v0[3])),
                         fmaxf(fmaxf(v1[0], v1[1]), fmaxf(v1[2], v1[3])));
#pragma unroll
        for (int off = 32; off > 0; off >>= 1) mx = fmaxf(mx, __shfl_xor(mx, off));
        float e[8];
        e[0] = __expf(v0[0] - mx); e[1] = __expf(v0[1] - mx);
        e[2] = __expf(v0[2] - mx); e[3] = __expf(v0[3] - mx);
        e[4] = __expf(v1[0] - mx); e[5] = __expf(v1[1] - mx);
        e[6] = __expf(v1[2] - mx); e[7] = __expf(v1[3] - mx);
        float sum = ((e[0] + e[1]) + (e[2] + e[3])) + ((e[4] + e[5]) + (e[6] + e[7]));
#pragma unroll
        for (int off = 32; off > 0; off >>= 1) sum += __shfl_xor(sum, off);
        float inv = 1.f / sum;
#pragma unroll
        for (int l = 0; l < 8; ++l) e[l] *= inv;
        float* arow = attn + (bh * NN + i0 + row) * NN + lane * 8;
        float4 o0; o0.x = e[0]; o0.y = e[1]; o0.z = e[2]; o0.w = e[3];
        float4 o1; o1.x = e[4]; o1.y = e[5]; o1.z = e[6]; o1.w = e[7];
        *(float4*)(arow) = o0;
        *(float4*)(arow + 4) = o1;
        uint4 pk;
        pk.x = cvt_pk_bf16(e[0], e[1]); pk.y = cvt_pk_bf16(e[2], e[3]);
        pk.z = cvt_pk_bf16(e[4], e[5]); pk.w = cvt_pk_bf16(e[6], e[7]);
        *(uint4*)(sab + row * 2064 + lane * 16) = pk;   // in-place after reads (lockstep wave)
    }
    __syncthreads();

    // ---- attn @ V: wave w = (part = w>>1 [V hi/lo], nh = w&1 [d half]); unrolled ----
    {
        int part = w >> 1, nh = w & 1;
        const unsigned short* vbase = (part == 0 ? vhi : vlo) + (bh * HDIM + nh * 16 + r) * NN;
        f32x4 acc = {0.f, 0.f, 0.f, 0.f};
#pragma unroll
        for (int kt = 0; kt < 16; ++kt) {
            bf16x8 af = *(bf16x8*)(sab + r * 2064 + kt * 64 + q2 * 16);
            bf16x8 bfg = *(const bf16x8*)(vbase + kt * 32 + q2 * 8);
            acc = __builtin_amdgcn_mfma_f32_16x16x32_bf16(af, bfg, acc, 0, 0, 0);
        }
#pragma unroll
        for (int reg = 0; reg < 4; ++reg)
            s_out[part][q2 * 4 + reg][nh * 16 + r] = acc[reg];
    }
    __syncthreads();

    // ---- ao write: channel = h*32+d ----
#pragma unroll
    for (int rep = 0; rep < 2; ++rep) {
        int idx = rep * 256 + t;
        int row = idx >> 5, d = idx & 31;
        ao[((size_t)b * NN + i0 + row) * HID + h * HDIM + d] =
            s_out[0][row][d] + s_out[1][row][d];
    }
}

// ---------- kernel 4: Wo + residual + LayerNorm + relu, 4 rows/block (untouched) ----------
__global__ __launch_bounds__(256) void k_final(
    const float* __restrict__ ao, const float* __restrict__ node_h,
    const float* __restrict__ Wo, const float* __restrict__ bo,
    const float* __restrict__ ln_g, const float* __restrict__ ln_b,
    float* __restrict__ out) {
    int blk = blockIdx.x;           // 512 blocks
    size_t bi0 = (size_t)blk * 4;
    int t = threadIdx.x;
    __shared__ __align__(16) float s_a[4][HID];
    __shared__ float s_red[4][4][2];
#pragma unroll
    for (int u = 0; u < 4; ++u)
        s_a[u][t] = ao[(bi0 + u) * HID + t];
    __syncthreads();
    float bov = bo[t];
    float o[4];
#pragma unroll
    for (int u = 0; u < 4; ++u) o[u] = bov;
#pragma unroll 4
    for (int rr = 0; rr < HID; ++rr) {
        float wo = Wo[rr * HID + t];
#pragma unroll
        for (int u = 0; u < 4; ++u) o[u] = fmaf(s_a[u][rr], wo, o[u]);
    }
    float g = ln_g[t], bb = ln_b[t];
    int wave = t >> 6, ln = t & 63;
    float x[4];
#pragma unroll
    for (int u = 0; u < 4; ++u) {
        x[u] = node_h[(bi0 + u) * HID + t] + o[u];
        float s1 = x[u], s2 = x[u] * x[u];
#pragma unroll
        for (int off = 32; off > 0; off >>= 1) { s1 += __shfl_xor(s1, off); s2 += __shfl_xor(s2, off); }
        if (ln == 0) { s_red[u][wave][0] = s1; s_red[u][wave][1] = s2; }
    }
    __syncthreads();
#pragma unroll
    for (int u = 0; u < 4; ++u) {
        float s1 = s_red[u][0][0] + s_red[u][1][0] + s_red[u][2][0] + s_red[u][3][0];
        float s2 = s_red[u][0][1] + s_red[u][1][1] + s_red[u][2][1] + s_red[u][3][1];
        float mean = s1 * (1.f / HID);
        float var = s2 * (1.f / HID) - mean * mean;
        float inv = rsqrtf(var + 1e-5f);
        float y = (x[u] - mean) * inv * g + bb;
        out[(bi0 + u) * HID + t] = fmaxf(y, 0.f);
    }
}

extern "C" void kernel_launch(void* const* d_in, const int* in_sizes, int n_in,
                              void* d_out, int out_size, void* d_ws, size_t ws_size,
                              hipStream_t stream) {
    const float* node_h = (const float*)d_in[0];
    const float* edge_x = (const float*)d_in[1];
    const int*   emask  = (const int*)d_in[2];
    const float* Wq = (const float*)d_in[3];
    const float* bq = (const float*)d_in[4];
    const float* Wk = (const float*)d_in[5];
    const float* bk = (const float*)d_in[6];
    const float* Wv = (const float*)d_in[7];
    const float* bv = (const float*)d_in[8];
    const float* We1 = (const float*)d_in[9];
    const float* be1 = (const float*)d_in[10];
    const float* We2 = (const float*)d_in[11];
    const float* be2 = (const float*)d_in[12];
    const float* Wo = (const float*)d_in[13];
    const float* bo = (const float*)d_in[14];
    const float* ln_g = (const float*)d_in[15];
    const float* ln_b = (const float*)d_in[16];

    float* out_x  = (float*)d_out;                              // [4,512,256]
    float* out_at = (float*)d_out + (size_t)BATCH * NN * HID;   // [4,8,512,512] (eb then attn)

    // ws high-water = 8.023 MB, byte-identical to the proven-safe R8/R13 layout.
    float* ws = (float*)d_ws;
    float* q = ws;                                          // 2 MB
    unsigned short* khi = (unsigned short*)(ws + 524288);   // 1 MB
    unsigned short* klo = khi + 524288;                     // 1 MB
    unsigned short* vhi = klo + 524288;                     // 1 MB
    unsigned short* vlo = vhi + 524288;                     // 1 MB
    float* ao = (float*)(vlo + 524288);                     // 2 MB
    unsigned short* W1P = (unsigned short*)(ao + 524288);   // 16 KB
    unsigned short* W2P = W1P + 8192;                       // 8 KB

    const int NBI = BATCH * NN;  // 2048

    hipLaunchKernelGGL(k_pack, dim3(1), dim3(256), 0, stream, We1, be1, We2, W1P, W2P);
    hipLaunchKernelGGL(k_ebqkv, dim3(2560), dim3(256), 0, stream,
                       edge_x, W1P, W2P, be2, out_at,
                       node_h, Wq, bq, Wk, bk, Wv, bv, q, khi, klo, vhi, vlo);
    hipLaunchKernelGGL(k_attn2, dim3(1024), dim3(256), 0, stream,
                       emask, q, khi, klo, vhi, vlo, out_at, ao);
    hipLaunchKernelGGL(k_final, dim3(NBI / 4), dim3(256), 0, stream,
                       ao, node_h, Wo, bo, ln_g, ln_b, out_x);
}

// Round 22
// 121.168 us; speedup vs baseline: 1.0910x; 1.0910x over previous
//
#include <hip/hip_runtime.h>

#define BATCH 4
#define NN 512
#define HID 256
#define EDIM 16
#define HEADS 8
#define HDIM 32

typedef __attribute__((ext_vector_type(8))) short bf16x8;
typedef __attribute__((ext_vector_type(4))) float f32x4;

__device__ inline unsigned short bf16_hi(float x){ return (unsigned short)(__float_as_uint(x)>>16); }
__device__ inline float bf16_f(unsigned short s){ return __uint_as_float(((unsigned)s)<<16); }
__device__ inline unsigned short bf16_rn(float x){
    unsigned u = __float_as_uint(x);
    unsigned r = u + 0x7FFFu + ((u>>16)&1u);
    return (unsigned short)(r>>16);
}
__device__ inline unsigned cvt_pk_bf16(float a, float b){
    unsigned d;
    asm("v_cvt_pk_bf16_f32 %0, %1, %2" : "=v"(d) : "v"(a), "v"(b));
    return d;
}
// split 8 floats into hi (trunc) and lo (RNE of remainder) bf16x8 fragments
__device__ inline void hilo8(float4 A, float4 B, bf16x8& hi, bf16x8& lo){
    float xs[8] = {A.x,A.y,A.z,A.w,B.x,B.y,B.z,B.w};
    unsigned hu[4], lu[4];
#pragma unroll
    for (int p = 0; p < 4; ++p){
        unsigned u0 = __float_as_uint(xs[2*p]), u1 = __float_as_uint(xs[2*p+1]);
        float h0 = __uint_as_float(u0 & 0xFFFF0000u);
        float h1 = __uint_as_float(u1 & 0xFFFF0000u);
        hu[p] = (u0 >> 16) | (u1 & 0xFFFF0000u);
        lu[p] = cvt_pk_bf16(xs[2*p] - h0, xs[2*p+1] - h1);
    }
    int4 hv; hv.x = hu[0]; hv.y = hu[1]; hv.z = hu[2]; hv.w = hu[3];
    int4 lv; lv.x = lu[0]; lv.y = lu[1]; lv.z = lu[2]; lv.w = lu[3];
    hi = *(bf16x8*)&hv; lo = *(bf16x8*)&lv;
}

// ---------- kernel 0: pack W1 (K=32: [W1hi(16); W1lo(15); be1]) + W2 bf16 B-frags ----------
__global__ void k_pack(const float* __restrict__ We1, const float* __restrict__ be1,
                       const float* __restrict__ We2,
                       unsigned short* __restrict__ W1P, unsigned short* __restrict__ W2P) {
    int t = threadIdx.x;  // 256
#pragma unroll
    for (int rep = 0; rep < 4; ++rep) {
        int p = rep * 256 + t;          // (ut, lane)
        int ut = p >> 6, lane = p & 63;
        int q = lane >> 4, r = lane & 15;
        int unit = ut * 16 + r;
#pragma unroll
        for (int j = 0; j < 8; ++j) {
            int k = q * 8 + j;
            unsigned short ov;
            if (k < 16) ov = bf16_hi(We1[k * HID + unit]);
            else if (k < 31) {
                float v = We1[(k - 16) * HID + unit];
                ov = bf16_rn(v - bf16_f(bf16_hi(v)));
            } else ov = bf16_rn(be1[unit]);
            W1P[p * 8 + j] = ov;
        }
    }
#pragma unroll
    for (int rep = 0; rep < 2; ++rep) {
        int p = rep * 256 + t;          // (kt, lane)
        int kt = p >> 6, lane = p & 63;
        int q = lane >> 4, r = lane & 15;
#pragma unroll
        for (int jj = 0; jj < 8; ++jj) {
            int unit = kt * 32 + q * 8 + jj;
            W2P[p * 8 + jj] = (r < 8) ? bf16_rn(We2[unit * HEADS + r]) : (unsigned short)0;
        }
    }
}

// ---------- kernel 1: FUSED eb + qkv; qkv blocks dispatched FIRST (LPT schedule) ----------
// qkv block latency ~2x eb block latency; front-loading the 512 long qkv blocks
// hides them fully under the 2048-block eb stream, leaving a short-block tail.
__global__ __launch_bounds__(256, 3) void k_ebqkv(
    const float* __restrict__ edge_x,
    const unsigned short* __restrict__ W1P, const unsigned short* __restrict__ W2P,
    const float* __restrict__ be2, float* __restrict__ eb,
    const float* __restrict__ node_h,
    const float* __restrict__ Wq, const float* __restrict__ bq,
    const float* __restrict__ Wk, const float* __restrict__ bk,
    const float* __restrict__ Wv, const float* __restrict__ bv,
    float* __restrict__ q,
    unsigned short* __restrict__ khi, unsigned short* __restrict__ klo,
    unsigned short* __restrict__ vhi, unsigned short* __restrict__ vlo) {
    __shared__ __align__(16) char smem[24576];   // overlay: eb 24 KB | qkv 4 KB
    int bid0 = blockIdx.x;
    int t = threadIdx.x;

    if (bid0 < 512) {
        // ================= qkv body (verbatim R13), blk = bid0 in [0,512) =================
        float (*s_h)[HID] = (float(*)[HID])smem;
        int blk = bid0;
        int b = blk >> 7, i0 = (blk & 127) << 2;
#pragma unroll
        for (int u = 0; u < 4; ++u)
            s_h[u][t] = node_h[((size_t)b * NN + i0 + u) * HID + t];
        __syncthreads();
        float aq[4], ak[4], av[4];
        float bqv = bq[t], bkv = bk[t], bvv = bv[t];
#pragma unroll
        for (int u = 0; u < 4; ++u) { aq[u] = bqv; ak[u] = bkv; av[u] = bvv; }
#pragma unroll 4
        for (int rr = 0; rr < HID; ++rr) {
            float wq = Wq[rr * HID + t], wk = Wk[rr * HID + t], wv = Wv[rr * HID + t];
#pragma unroll
            for (int u = 0; u < 4; ++u) {
                float x = s_h[u][rr];
                aq[u] = fmaf(x, wq, aq[u]);
                ak[u] = fmaf(x, wk, ak[u]);
                av[u] = fmaf(x, wv, av[u]);
            }
        }
        int h = t >> 5, d = t & 31;
#pragma unroll
        for (int u = 0; u < 4; ++u) {
            size_t idx = ((size_t)(b * HEADS + h) * NN + i0 + u) * HDIM + d;
            q[idx] = aq[u];
            unsigned short kh = bf16_hi(ak[u]);
            khi[idx] = kh;
            klo[idx] = bf16_rn(ak[u] - bf16_f(kh));
            size_t vidx = ((size_t)(b * HEADS + h) * HDIM + d) * NN + i0 + u;
            unsigned short vh = bf16_hi(av[u]);
            vhi[vidx] = vh;
            vlo[vidx] = bf16_rn(av[u] - bf16_f(vh));
        }
        return;
    }

    // ================= eb body (verbatim R13/R15), eid = bid0 - 512 in [0,2048) =================
    unsigned short* sW1 = (unsigned short*)smem;            // 16 KB
    unsigned short* sW2 = (unsigned short*)(smem + 16384);  // 8 KB
    int eid = bid0 - 512;
    int b = eid >> 9, i0 = ((eid >> 2) & 127) << 2, jq = eid & 3;
    int w = t >> 6, lane = t & 63;
    int q2 = lane >> 4, r = lane & 15;

    {
        const float4* s1 = (const float4*)W1P;
        float4* d1 = (float4*)sW1;
#pragma unroll
        for (int rep = 0; rep < 4; ++rep) d1[rep * 256 + t] = s1[rep * 256 + t];
        const float4* s2 = (const float4*)W2P;
        float4* d2 = (float4*)sW2;
#pragma unroll
        for (int rep = 0; rep < 2; ++rep) d2[rep * 256 + t] = s2[rep * 256 + t];
    }
    __syncthreads();

    float be2r = (r < 8) ? be2[r] : 0.f;
    const char* wb1 = (const char*)sW1 + lane * 16;
    const char* wb2 = (const char*)sW2 + lane * 16;

    size_t xbase = (((size_t)b * NN + i0 + w) * NN) * EDIM + (size_t)((q2 & 1) * 8);
    const f32x4 zero4 = {0.f, 0.f, 0.f, 0.f};

    for (int sc = 0; sc < 2; ++sc) {
        int cc0 = jq * 8 + sc * 4;
        float4 xv[8];
#pragma unroll
        for (int x = 0; x < 4; ++x) {
            const float4* px = (const float4*)(edge_x + xbase + (size_t)((cc0 + x) * 16 + r) * EDIM);
            xv[2 * x]     = px[0];
            xv[2 * x + 1] = px[1];
        }
        bf16x8 bx[4];
#pragma unroll
        for (int x = 0; x < 4; ++x) {
            unsigned u0 = cvt_pk_bf16(xv[2*x].x, xv[2*x].y);
            unsigned u1 = cvt_pk_bf16(xv[2*x].z, xv[2*x].w);
            unsigned u2 = cvt_pk_bf16(xv[2*x+1].x, xv[2*x+1].y);
            unsigned u3 = cvt_pk_bf16(xv[2*x+1].z, xv[2*x+1].w);
            if (q2 == 3) u3 = (u3 & 0xFFFFu) | 0x3F800000u;   // slot31 = 1.0 (be1)
            int4 bxi; bxi.x = u0; bxi.y = u1; bxi.z = u2; bxi.w = u3;
            bx[x] = *(bf16x8*)&bxi;
        }
        f32x4 acc0[4], acc1[4];
#pragma unroll
        for (int x = 0; x < 4; ++x) {
            acc0[x] = (f32x4){be2r, be2r, be2r, be2r};
            acc1[x] = zero4;
        }
#pragma unroll
        for (int ktp = 0; ktp < 8; ++ktp) {
            bf16x8 wa = *(const bf16x8*)(wb1 + (2 * ktp) * 1024);
            bf16x8 wb = *(const bf16x8*)(wb1 + (2 * ktp + 1) * 1024);
            bf16x8 w2 = *(const bf16x8*)(wb2 + ktp * 1024);
#pragma unroll
            for (int x = 0; x < 4; ++x) {
                f32x4 c0 = __builtin_amdgcn_mfma_f32_16x16x32_bf16(wa, bx[x], zero4, 0, 0, 0);
                f32x4 c1 = __builtin_amdgcn_mfma_f32_16x16x32_bf16(wb, bx[x], zero4, 0, 0, 0);
                unsigned P0 = cvt_pk_bf16(fmaxf(c0[0], 0.f), fmaxf(c0[1], 0.f));
                unsigned P1 = cvt_pk_bf16(fmaxf(c0[2], 0.f), fmaxf(c0[3], 0.f));
                unsigned Q0 = cvt_pk_bf16(fmaxf(c1[0], 0.f), fmaxf(c1[1], 0.f));
                unsigned Q1 = cvt_pk_bf16(fmaxf(c1[2], 0.f), fmaxf(c1[3], 0.f));
                // 16x16 transpose across the four 16-lane rows (zero LDS):
                asm("v_permlane32_swap_b32 %0, %1" : "+v"(P0), "+v"(Q0));
                asm("v_permlane16_swap_b32 %0, %1" : "+v"(P0), "+v"(Q0));
                asm("v_permlane32_swap_b32 %0, %1" : "+v"(P1), "+v"(Q1));
                asm("v_permlane16_swap_b32 %0, %1" : "+v"(P1), "+v"(Q1));
                int4 ai; ai.x = (int)P0; ai.y = (int)P1; ai.z = (int)Q0; ai.w = (int)Q1;
                if (ktp & 1)
                    acc1[x] = __builtin_amdgcn_mfma_f32_16x16x32_bf16(*(bf16x8*)&ai, w2, acc1[x], 0, 0, 0);
                else
                    acc0[x] = __builtin_amdgcn_mfma_f32_16x16x32_bf16(*(bf16x8*)&ai, w2, acc0[x], 0, 0, 0);
            }
        }
        if (r < 8) {
#pragma unroll
            for (int x = 0; x < 4; ++x) {
                f32x4 a = acc0[x] + acc1[x];
                *(f32x4*)(eb + (((size_t)(b * HEADS + r) * NN) + (i0 + w)) * NN + (cc0 + x) * 16 + q2 * 4) = a;
            }
        }
    }
}

// ---------- kernel 3: scores(MFMA) + softmax + attn@V(MFMA); unrolled (R21) ----------
__global__ __launch_bounds__(256, 4) void k_attn2(
    const int* __restrict__ emask, const float* __restrict__ q,
    const unsigned short* __restrict__ khi, const unsigned short* __restrict__ klo,
    const unsigned short* __restrict__ vhi, const unsigned short* __restrict__ vlo,
    float* attn, float* __restrict__ ao) {
    int orig = blockIdx.x;                      // 1024 blocks (1024 % 8 == 0: bijective)
    int bid = ((orig & 7) << 7) | (orig >> 3);  // xcd * 128 + orig/8
    int b = bid >> 8, h = (bid >> 5) & 7, ic = bid & 31;
    int i0 = ic << 4;
    int t = threadIdx.x, w = t >> 6, lane = t & 63;
    int q2 = lane >> 4, r = lane & 15;
    size_t bh = (size_t)b * HEADS + h;

    __shared__ __align__(16) float s_sc[16][516];   // 33024 B
    __shared__ float s_out[2][16][33];              // 4224 B
    char* sab = (char*)&s_sc[0][0];                 // row stride 2064 B

    // Q A-frag (hi/lo): lane 16*q2+r holds Q[row=r][d=q2*8..+7]
    bf16x8 qhi, qlo;
    {
        const float4* qp = (const float4*)(q + ((bh * NN) + i0 + r) * HDIM + q2 * 8);
        hilo8(qp[0], qp[1], qhi, qlo);
    }

    const float scale = 0.17677669529663687f;  // 1/sqrt(32)
    const int* mbase = emask + ((size_t)b * NN + i0) * NN;
    const float* ebase = attn + (bh * NN + i0) * NN;
#pragma unroll
    for (int c = 0; c < 8; ++c) {
        int jt = w * 8 + c;
        size_t kidx = (bh * NN + jt * 16 + r) * HDIM + q2 * 8;
        bf16x8 kh8 = *(const bf16x8*)(khi + kidx);
        bf16x8 kl8 = *(const bf16x8*)(klo + kidx);
        f32x4 cc = {0.f, 0.f, 0.f, 0.f};
        cc = __builtin_amdgcn_mfma_f32_16x16x32_bf16(qhi, kh8, cc, 0, 0, 0);
        cc = __builtin_amdgcn_mfma_f32_16x16x32_bf16(qhi, kl8, cc, 0, 0, 0);
        cc = __builtin_amdgcn_mfma_f32_16x16x32_bf16(qlo, kh8, cc, 0, 0, 0);
        int j = jt * 16 + r;
#pragma unroll
        for (int reg = 0; reg < 4; ++reg) {
            int row = q2 * 4 + reg;
            float s = cc[reg] * scale;
            s = s > 0.f ? s : 0.2f * s;
            s += ebase[row * NN + j];
            bool valid = (mbase[row * NN + j] != 0) || (j == i0 + row);
            s_sc[row][j] = valid ? s : -1e9f;
        }
    }
    __syncthreads();

    // ---- softmax: wave w rows w*4..w*4+3; lane owns j = lane*8..lane*8+7 ----
#pragma unroll
    for (int rr = 0; rr < 4; ++rr) {
        int row = w * 4 + rr;
        f32x4 v0 = *(f32x4*)&s_sc[row][lane * 8];
        f32x4 v1 = *(f32x4*)&s_sc[row][lane * 8 + 4];
        float mx = fmaxf(fmaxf(fmaxf(v0[0], v0[1]), fmaxf(v0[2], v0[3])),
                         fmaxf(fmaxf(v1[0], v1[1]), fmaxf(v1[2], v1[3])));
#pragma unroll
        for (int off = 32; off > 0; off >>= 1) mx = fmaxf(mx, __shfl_xor(mx, off));
        float e[8];
        e[0] = __expf(v0[0] - mx); e[1] = __expf(v0[1] - mx);
        e[2] = __expf(v0[2] - mx); e[3] = __expf(v0[3] - mx);
        e[4] = __expf(v1[0] - mx); e[5] = __expf(v1[1] - mx);
        e[6] = __expf(v1[2] - mx); e[7] = __expf(v1[3] - mx);
        float sum = ((e[0] + e[1]) + (e[2] + e[3])) + ((e[4] + e[5]) + (e[6] + e[7]));
#pragma unroll
        for (int off = 32; off > 0; off >>= 1) sum += __shfl_xor(sum, off);
        float inv = 1.f / sum;
#pragma unroll
        for (int l = 0; l < 8; ++l) e[l] *= inv;
        float* arow = attn + (bh * NN + i0 + row) * NN + lane * 8;
        float4 o0; o0.x = e[0]; o0.y = e[1]; o0.z = e[2]; o0.w = e[3];
        float4 o1; o1.x = e[4]; o1.y = e[5]; o1.z = e[6]; o1.w = e[7];
        *(float4*)(arow) = o0;
        *(float4*)(arow + 4) = o1;
        uint4 pk;
        pk.x = cvt_pk_bf16(e[0], e[1]); pk.y = cvt_pk_bf16(e[2], e[3]);
        pk.z = cvt_pk_bf16(e[4], e[5]); pk.w = cvt_pk_bf16(e[6], e[7]);
        *(uint4*)(sab + row * 2064 + lane * 16) = pk;   // in-place after reads (lockstep wave)
    }
    __syncthreads();

    // ---- attn @ V: wave w = (part = w>>1 [V hi/lo], nh = w&1 [d half]) ----
    {
        int part = w >> 1, nh = w & 1;
        const unsigned short* vbase = (part == 0 ? vhi : vlo) + (bh * HDIM + nh * 16 + r) * NN;
        f32x4 acc = {0.f, 0.f, 0.f, 0.f};
#pragma unroll
        for (int kt = 0; kt < 16; ++kt) {
            bf16x8 af = *(bf16x8*)(sab + r * 2064 + kt * 64 + q2 * 16);
            bf16x8 bfg = *(const bf16x8*)(vbase + kt * 32 + q2 * 8);
            acc = __builtin_amdgcn_mfma_f32_16x16x32_bf16(af, bfg, acc, 0, 0, 0);
        }
#pragma unroll
        for (int reg = 0; reg < 4; ++reg)
            s_out[part][q2 * 4 + reg][nh * 16 + r] = acc[reg];
    }
    __syncthreads();

    // ---- ao write: channel = h*32+d ----
#pragma unroll
    for (int rep = 0; rep < 2; ++rep) {
        int idx = rep * 256 + t;
        int row = idx >> 5, d = idx & 31;
        ao[((size_t)b * NN + i0 + row) * HID + h * HDIM + d] =
            s_out[0][row][d] + s_out[1][row][d];
    }
}

// ---------- kernel 4: Wo + residual + LayerNorm + relu, 4 rows/block (untouched) ----------
__global__ __launch_bounds__(256) void k_final(
    const float* __restrict__ ao, const float* __restrict__ node_h,
    const float* __restrict__ Wo, const float* __restrict__ bo,
    const float* __restrict__ ln_g, const float* __restrict__ ln_b,
    float* __restrict__ out) {
    int blk = blockIdx.x;           // 512 blocks
    size_t bi0 = (size_t)blk * 4;
    int t = threadIdx.x;
    __shared__ __align__(16) float s_a[4][HID];
    __shared__ float s_red[4][4][2];
#pragma unroll
    for (int u = 0; u < 4; ++u)
        s_a[u][t] = ao[(bi0 + u) * HID + t];
    __syncthreads();
    float bov = bo[t];
    float o[4];
#pragma unroll
    for (int u = 0; u < 4; ++u) o[u] = bov;
#pragma unroll 4
    for (int rr = 0; rr < HID; ++rr) {
        float wo = Wo[rr * HID + t];
#pragma unroll
        for (int u = 0; u < 4; ++u) o[u] = fmaf(s_a[u][rr], wo, o[u]);
    }
    float g = ln_g[t], bb = ln_b[t];
    int wave = t >> 6, ln = t & 63;
    float x[4];
#pragma unroll
    for (int u = 0; u < 4; ++u) {
        x[u] = node_h[(bi0 + u) * HID + t] + o[u];
        float s1 = x[u], s2 = x[u] * x[u];
#pragma unroll
        for (int off = 32; off > 0; off >>= 1) { s1 += __shfl_xor(s1, off); s2 += __shfl_xor(s2, off); }
        if (ln == 0) { s_red[u][wave][0] = s1; s_red[u][wave][1] = s2; }
    }
    __syncthreads();
#pragma unroll
    for (int u = 0; u < 4; ++u) {
        float s1 = s_red[u][0][0] + s_red[u][1][0] + s_red[u][2][0] + s_red[u][3][0];
        float s2 = s_red[u][0][1] + s_red[u][1][1] + s_red[u][2][1] + s_red[u][3][1];
        float mean = s1 * (1.f / HID);
        float var = s2 * (1.f / HID) - mean * mean;
        float inv = rsqrtf(var + 1e-5f);
        float y = (x[u] - mean) * inv * g + bb;
        out[(bi0 + u) * HID + t] = fmaxf(y, 0.f);
    }
}

extern "C" void kernel_launch(void* const* d_in, const int* in_sizes, int n_in,
                              void* d_out, int out_size, void* d_ws, size_t ws_size,
                              hipStream_t stream) {
    const float* node_h = (const float*)d_in[0];
    const float* edge_x = (const float*)d_in[1];
    const int*   emask  = (const int*)d_in[2];
    const float* Wq = (const float*)d_in[3];
    const float* bq = (const float*)d_in[4];
    const float* Wk = (const float*)d_in[5];
    const float* bk = (const float*)d_in[6];
    const float* Wv = (const float*)d_in[7];
    const float* bv = (const float*)d_in[8];
    const float* We1 = (const float*)d_in[9];
    const float* be1 = (const float*)d_in[10];
    const float* We2 = (const float*)d_in[11];
    const float* be2 = (const float*)d_in[12];
    const float* Wo = (const float*)d_in[13];
    const float* bo = (const float*)d_in[14];
    const float* ln_g = (const float*)d_in[15];
    const float* ln_b = (const float*)d_in[16];

    float* out_x  = (float*)d_out;                              // [4,512,256]
    float* out_at = (float*)d_out + (size_t)BATCH * NN * HID;   // [4,8,512,512] (eb then attn)

    // ws high-water = 8.023 MB, byte-identical to the proven-safe R8/R13 layout.
    float* ws = (float*)d_ws;
    float* q = ws;                                          // 2 MB
    unsigned short* khi = (unsigned short*)(ws + 524288);   // 1 MB
    unsigned short* klo = khi + 524288;                     // 1 MB
    unsigned short* vhi = klo + 524288;                     // 1 MB
    unsigned short* vlo = vhi + 524288;                     // 1 MB
    float* ao = (float*)(vlo + 524288);                     // 2 MB
    unsigned short* W1P = (unsigned short*)(ao + 524288);   // 16 KB
    unsigned short* W2P = W1P + 8192;                       // 8 KB

    const int NBI = BATCH * NN;  // 2048

    hipLaunchKernelGGL(k_pack, dim3(1), dim3(256), 0, stream, We1, be1, We2, W1P, W2P);
    hipLaunchKernelGGL(k_ebqkv, dim3(2560), dim3(256), 0, stream,
                       edge_x, W1P, W2P, be2, out_at,
                       node_h, Wq, bq, Wk, bk, Wv, bv, q, khi, klo, vhi, vlo);
    hipLaunchKernelGGL(k_attn2, dim3(1024), dim3(256), 0, stream,
                       emask, q, khi, klo, vhi, vlo, out_at, ao);
    hipLaunchKernelGGL(k_final, dim3(NBI / 4), dim3(256), 0, stream,
                       ao, node_h, Wo, bo, ln_g, ln_b, out_x);
}